// Round 7
// baseline (902.517 us; speedup 1.0000x reference)
//
#include <hip/hip_runtime.h>

typedef unsigned int uint32;
typedef unsigned short u16;

// Problem constants
#define DD    2048
#define LP1   513
#define TT    65
#define FOURD 8192
#define NWG   256
#define SLOTW 32      // u32 per global slot (8 used, padded to 128 B)
#define LREL  9       // LDS relay stride per slot (9 u32: bank-conflict-free)

typedef __attribute__((ext_vector_type(8))) short short8;   // 8 bf16 (4 VGPRs)
typedef __attribute__((ext_vector_type(4))) float f32x4;

// ---------- helpers ----------
__device__ __forceinline__ float frcp(float x) { return __builtin_amdgcn_rcpf(x); }
__device__ __forceinline__ float sigm(float x) {
    return frcp(1.f + exp2f(-1.4426950408889634f * x));
}
__device__ __forceinline__ float tanh_fast(float x) {
    float e = exp2f(2.8853900817779268f * x);    // e^(2x)
    return fmaf(-2.f, frcp(1.f + e), 1.f);       // 1 - 2/(1+e^(2x))
}
__device__ __forceinline__ float bflo(uint32 w) {
    union { uint32 i; float f; } c; c.i = w << 16; return c.f;
}
__device__ __forceinline__ float bfhi(uint32 w) {
    union { uint32 i; float f; } c; c.i = w & 0xffff0000u; return c.f;
}
__device__ __forceinline__ uint32 f2bf(float f) {   // RNE, returns low 16
    union { float f; uint32 i; } c; c.f = f;
    return (c.i + 0x7fffu + ((c.i >> 16) & 1u)) >> 16;
}
__device__ __forceinline__ uint32 pack2(float a, float b) {
    return f2bf(a) | (f2bf(b) << 16);
}

#if __has_builtin(__builtin_amdgcn_fdot2_f32_bf16)
#define HAVE_DOT2 1
typedef __attribute__((ext_vector_type(2))) __bf16 bf16x2;
__device__ __forceinline__ float dot2bf(uint32 a, uint32 b, float c) {
    union { uint32 u; bf16x2 v; } x, y; x.u = a; y.u = b;
    return __builtin_amdgcn_fdot2_f32_bf16(x.v, y.v, c, false);
}
#endif

// ---------- K0: xg[t][r] = b_ih[r]+b_hh[r]+W_ih[r,:]@x_t ; zero hX tags ------
__global__ __launch_bounds__(256) void xg_kernel(
    const float* __restrict__ W_ih, const float* __restrict__ b_ih,
    const float* __restrict__ b_hh, const float* __restrict__ seq,
    const int* __restrict__ pos, float* __restrict__ xg,
    uint32* __restrict__ hX)
{
    if (blockIdx.y < 2)   // 2*32 blocks x 256 thr = 16384 = 2*NWG*SLOTW words
        hX[blockIdx.y * 8192 + blockIdx.x * 256 + threadIdx.x] = 0u;
    int t = blockIdx.y;
    int r = blockIdx.x * 256 + threadIdx.x;   // [0, 8192)
    float x0, x1, x2;
    if (t == 0) { x0 = 0.f; x1 = 0.f; x2 = 1.f; }   // special symbol
    else {
        int p = pos[t - 1];
        x0 = seq[p * 3 + 0]; x1 = seq[p * 3 + 1]; x2 = seq[p * 3 + 2];
    }
    float acc = b_ih[r] + b_hh[r];
    acc = fmaf(W_ih[r * 3 + 0], x0, acc);
    acc = fmaf(W_ih[r * 3 + 1], x1, acc);
    acc = fmaf(W_ih[r * 3 + 2], x2, acc);
    xg[(size_t)t * FOURD + r] = acc;
}

// ---------- K1/K3: MFMA GEMM  C[M,N] = A[M,K]@B[N,K]^T + bias, fp32 inputs ---
// 64x64 tile, BK=64, 2-phase prefetch (R5/R6-verified); fp32->bf16 conversion
// fused into the LDS-staging write (R0-R2-verified composition).
#define GLSTR 72
__global__ __launch_bounds__(256) void gemm_bf16_kernel(
    const float* __restrict__ A, const float* __restrict__ B,
    const float* __restrict__ bias, float* __restrict__ C,
    int M, int N, int K)
{
    __shared__ u16 As[64 * GLSTR];
    __shared__ u16 Bs[64 * GLSTR];
    int tid = threadIdx.x;
    int wave = tid >> 6, lane = tid & 63;
    int m0 = blockIdx.y * 64, n0 = blockIdx.x * 64;
    int wm = (wave >> 1) * 32, wn = (wave & 1) * 32;
    int srow = tid >> 2, scol = (tid & 3) * 16;   // 16 fp32 elems per thread

    f32x4 acc[2][2] = {};
    int fr = lane & 15, fq = (lane >> 4) * 8;
    int am = m0 + srow;
    const float4* ap = (const float4*)(A + (size_t)am * K + scol);
    const float4* bp = (const float4*)(B + (size_t)(n0 + srow) * K + scol);

    // prologue: tile 0 (4 consecutive float4 per operand per thread)
    float4 a0 = {0,0,0,0}, a1 = a0, a2 = a0, a3 = a0, b0, b1, b2, b3;
    if (am < M) { a0 = ap[0]; a1 = ap[1]; a2 = ap[2]; a3 = ap[3]; }
    b0 = bp[0]; b1 = bp[1]; b2 = bp[2]; b3 = bp[3];

    for (int k0 = 0; k0 < K; k0 += 64) {
        __syncthreads();   // previous tile's fragment reads done
        {
            uint4* ad = (uint4*)(As + srow * GLSTR + scol);
            uint4 o;
            o.x = pack2(a0.x, a0.y); o.y = pack2(a0.z, a0.w);
            o.z = pack2(a1.x, a1.y); o.w = pack2(a1.z, a1.w);
            ad[0] = o;
            o.x = pack2(a2.x, a2.y); o.y = pack2(a2.z, a2.w);
            o.z = pack2(a3.x, a3.y); o.w = pack2(a3.z, a3.w);
            ad[1] = o;
            uint4* bd = (uint4*)(Bs + srow * GLSTR + scol);
            o.x = pack2(b0.x, b0.y); o.y = pack2(b0.z, b0.w);
            o.z = pack2(b1.x, b1.y); o.w = pack2(b1.z, b1.w);
            bd[0] = o;
            o.x = pack2(b2.x, b2.y); o.y = pack2(b2.z, b2.w);
            o.z = pack2(b3.x, b3.y); o.w = pack2(b3.z, b3.w);
            bd[1] = o;
        }
        __syncthreads();

        // issue next tile's loads (overlap with MFMA below)
        if (k0 + 64 < K) {
            int off = (k0 + 64) >> 2;       // float4 index of element k0+64
            if (am < M) { a0 = ap[off]; a1 = ap[off+1]; a2 = ap[off+2]; a3 = ap[off+3]; }
            b0 = bp[off]; b1 = bp[off+1]; b2 = bp[off+2]; b3 = bp[off+3];
        }

        #pragma unroll
        for (int kk = 0; kk < 64; kk += 32) {
            short8 af0 = *(const short8*)(As + (wm + fr) * GLSTR + kk + fq);
            short8 af1 = *(const short8*)(As + (wm + 16 + fr) * GLSTR + kk + fq);
            short8 bf0 = *(const short8*)(Bs + (wn + fr) * GLSTR + kk + fq);
            short8 bf1 = *(const short8*)(Bs + (wn + 16 + fr) * GLSTR + kk + fq);
            acc[0][0] = __builtin_amdgcn_mfma_f32_16x16x32_bf16(af0, bf0, acc[0][0], 0, 0, 0);
            acc[0][1] = __builtin_amdgcn_mfma_f32_16x16x32_bf16(af0, bf1, acc[0][1], 0, 0, 0);
            acc[1][0] = __builtin_amdgcn_mfma_f32_16x16x32_bf16(af1, bf0, acc[1][0], 0, 0, 0);
            acc[1][1] = __builtin_amdgcn_mfma_f32_16x16x32_bf16(af1, bf1, acc[1][1], 0, 0, 0);
        }
    }

    int cn = lane & 15, cr = (lane >> 4) * 4;
    #pragma unroll
    for (int i = 0; i < 2; i++) {
        #pragma unroll
        for (int r = 0; r < 4; r++) {
            int m = m0 + wm + i * 16 + cr + r;
            if (m < M) {
                #pragma unroll
                for (int j = 0; j < 2; j++) {
                    int n = n0 + wn + j * 16 + cn;
                    C[(size_t)m * N + n] = acc[i][j][r] + bias[n];
                }
            }
        }
    }
}

// ---------- K2: fused persistent LSTM, barrier-free dataflow -----------------
// 256 WGs x 256 thr. Weights live in REGISTERS (128 VGPR/thread, loaded once).
// Exchange: u32 flag-in-data word = (tag16 << 16) | bf16(h).
//   publish: lane<2 of each wave stores its dim's word, relaxed agent scope.
//   phase 1: thread tid polls GLOBAL slot tid (8 words) until tag>=t, then
//            relays the raw words into the LDS relay (tags travel with data).
//   phase 2: each thread spins on the 32 LDS words (4 slots) it needs, makes
//            packed bf16 pairs in registers. NO __syncthreads in the loop —
//            waves proceed on data availability (wave-granularity induction:
//            observing tag t+2 everywhere implies all waves consumed tag t+1,
//            so the 2-step double-buffer gap is overwrite-safe at both the
//            global and LDS level).
__global__ __launch_bounds__(256, 1) void lstm_fused_kernel(
    const float* __restrict__ Whh, const float* __restrict__ init_h,
    const float* __restrict__ xg, uint32* __restrict__ hX,
    float* __restrict__ outH)
{
    __shared__ float  xg_s[TT * 32];          // 8.3 KB
    __shared__ float  ho_s[TT * 8];           // 2.1 KB deferred h out
    __shared__ uint32 hx_s[2 * NWG * LREL];   // 18.4 KB LDS relay (dbuf)

    int tid = threadIdx.x;
    int b = blockIdx.x;                  // owns dims 8b..8b+7
    int wave = tid >> 6, lane = tid & 63;
    int jj = lane & 1;
    int dl = 2 * wave + jj;              // local dim 0..7

    // ---- zero LDS relay tags; stage xg slice
    for (int idx = tid; idx < 2 * NWG * LREL; idx += 256) hx_s[idx] = 0u;
    for (int idx = tid; idx < TT * 32; idx += 256) {
        int t = idx >> 5, rr = idx & 31, g = rr >> 3, j = rr & 7;
        xg_s[idx] = xg[(size_t)t * FOURD + g * DD + 8 * b + j];
    }

    // ---- weights -> registers: w[g][q][i] = 8 bf16 (uint4) for
    //      row (g*DD + 8b + 2*wave + q), k = i*512 + lane*8 .. +7
    uint4 w[4][2][4];
    #pragma unroll
    for (int g = 0; g < 4; g++)
        #pragma unroll
        for (int q = 0; q < 2; q++) {
            const float* row =
                Whh + ((size_t)(g * DD + 8 * b + 2 * wave + q)) * DD;
            #pragma unroll
            for (int i = 0; i < 4; i++) {
                const float4* p = (const float4*)(row + i * 512 + lane * 8);
                float4 x = p[0], y = p[1];
                uint4 o;
                o.x = pack2(x.x, x.y); o.y = pack2(x.z, x.w);
                o.z = pack2(y.x, y.y); o.w = pack2(y.z, y.w);
                w[g][q][i] = o;
            }
        }
    __syncthreads();   // xg_s + relay-zero ready (once, before the loop)

    float cst = 0.f;

    for (int t = 0; t < TT; t++) {
        // hp[i][p] = packed bf16 pair for k = i*512 + lane*8 + {2p, 2p+1}
        uint32 hp[4][4];
        if (t == 0) {
            #pragma unroll
            for (int i = 0; i < 4; i++) {
                const float4* p = (const float4*)(init_h + i * 512 + lane * 8);
                float4 x = p[0], y = p[1];
                hp[i][0] = pack2(x.x, x.y); hp[i][1] = pack2(x.z, x.w);
                hp[i][2] = pack2(y.x, y.y); hp[i][3] = pack2(y.z, y.w);
            }
        } else {
            // ---- phase 1: relay global slot 'tid' into the LDS relay
            const uint32* gs =
                hX + ((size_t)(((t - 1) & 1) * NWG + tid)) * SLOTW;
            uint32 gv[8];
            #pragma unroll
            for (int j = 0; j < 8; j++)
                gv[j] = __hip_atomic_load(gs + j, __ATOMIC_RELAXED,
                                          __HIP_MEMORY_SCOPE_AGENT);
            for (;;) {
                bool ok = true;
                #pragma unroll
                for (int j = 0; j < 8; j++) ok &= ((gv[j] >> 16) >= (uint32)t);
                if (ok) break;
                __builtin_amdgcn_s_sleep(1);
                #pragma unroll
                for (int j = 0; j < 8; j++)
                    if ((gv[j] >> 16) < (uint32)t)
                        gv[j] = __hip_atomic_load(gs + j, __ATOMIC_RELAXED,
                                                  __HIP_MEMORY_SCOPE_AGENT);
            }
            uint32* lb = hx_s + (t & 1) * (NWG * LREL);
            #pragma unroll
            for (int j = 0; j < 8; j++)
                __hip_atomic_store(lb + tid * LREL + j, gv[j],
                                   __ATOMIC_RELAXED,
                                   __HIP_MEMORY_SCOPE_WORKGROUP);

            // ---- phase 2: collect my 4 slots from the LDS relay
            #pragma unroll
            for (int i = 0; i < 4; i++) {
                const uint32* sl = lb + (i * 64 + lane) * LREL;
                uint32 hv[8];
                #pragma unroll
                for (int j = 0; j < 8; j++)
                    hv[j] = __hip_atomic_load(sl + j, __ATOMIC_RELAXED,
                                              __HIP_MEMORY_SCOPE_WORKGROUP);
                for (;;) {
                    bool ok = true;
                    #pragma unroll
                    for (int j = 0; j < 8; j++)
                        ok &= ((hv[j] >> 16) >= (uint32)t);
                    if (ok) break;
                    #pragma unroll
                    for (int j = 0; j < 8; j++)
                        if ((hv[j] >> 16) < (uint32)t)
                            hv[j] = __hip_atomic_load(
                                sl + j, __ATOMIC_RELAXED,
                                __HIP_MEMORY_SCOPE_WORKGROUP);
                }
                hp[i][0] = (hv[0] & 0xffffu) | (hv[1] << 16);
                hp[i][1] = (hv[2] & 0xffffu) | (hv[3] << 16);
                hp[i][2] = (hv[4] & 0xffffu) | (hv[5] << 16);
                hp[i][3] = (hv[6] & 0xffffu) | (hv[7] << 16);
            }
        }

        // ---- 8 partial dot products (weights in registers)
        float a[4][2];
        #pragma unroll
        for (int g = 0; g < 4; g++)
            #pragma unroll
            for (int q = 0; q < 2; q++) {
                float s = 0.f;
                #pragma unroll
                for (int i = 0; i < 4; i++) {
                    uint4 ww = w[g][q][i];
#ifdef HAVE_DOT2
                    s = dot2bf(ww.x, hp[i][0], s);
                    s = dot2bf(ww.y, hp[i][1], s);
                    s = dot2bf(ww.z, hp[i][2], s);
                    s = dot2bf(ww.w, hp[i][3], s);
#else
                    s = fmaf(bflo(ww.x), bflo(hp[i][0]), s);
                    s = fmaf(bfhi(ww.x), bfhi(hp[i][0]), s);
                    s = fmaf(bflo(ww.y), bflo(hp[i][1]), s);
                    s = fmaf(bfhi(ww.y), bfhi(hp[i][1]), s);
                    s = fmaf(bflo(ww.z), bflo(hp[i][2]), s);
                    s = fmaf(bfhi(ww.z), bfhi(hp[i][2]), s);
                    s = fmaf(bflo(ww.w), bflo(hp[i][3]), s);
                    s = fmaf(bfhi(ww.w), bfhi(hp[i][3]), s);
#endif
                }
                a[g][q] = s;
            }

        // butterfly reduce over 64 lanes
        #pragma unroll
        for (int off = 1; off < 64; off <<= 1) {
            #pragma unroll
            for (int g = 0; g < 4; g++) {
                a[g][0] += __shfl_xor(a[g][0], off);
                a[g][1] += __shfl_xor(a[g][1], off);
            }
        }
        float si = jj ? a[0][1] : a[0][0];
        float sf = jj ? a[1][1] : a[1][0];
        float sg = jj ? a[2][1] : a[2][0];
        float so = jj ? a[3][1] : a[3][0];
        int xb = t * 32;
        si += xg_s[xb + dl];      sf += xg_s[xb + 8 + dl];
        sg += xg_s[xb + 16 + dl]; so += xg_s[xb + 24 + dl];
        float ig = sigm(si), fg = sigm(sf), gg = tanh_fast(sg), og = sigm(so);
        cst = fmaf(fg, cst, ig * gg);
        float hh = og * tanh_fast(cst);
        if (lane < 2) {
            uint32 wrd = ((uint32)(t + 1) << 16) | f2bf(hh);
            __hip_atomic_store(
                &hX[((size_t)((t & 1) * NWG + b)) * SLOTW + dl], wrd,
                __ATOMIC_RELAXED, __HIP_MEMORY_SCOPE_AGENT);
            ho_s[t * 8 + dl] = hh;            // deferred fp32 h (LDS)
        }
    }

    // ---- deferred outH writeback
    __syncthreads();
    for (int idx = tid; idx < TT * 8; idx += 256) {
        int t = idx >> 3, j = idx & 7;
        outH[(size_t)t * DD + 8 * b + j] = ho_s[idx];
    }
}

// ---------- K4: logits[t][l] = v_b + sum_v vw[v]*tanh(enc_proj[l][v]+Dm[t][v])
__global__ __launch_bounds__(256) void ptr_kernel(
    const float* __restrict__ enc_proj, const float* __restrict__ Dm,
    const float* __restrict__ vw, const float* __restrict__ vb,
    float* __restrict__ outL)
{
    __shared__ float vw_s[DD];        // 8 KB
    __shared__ float Dm_s[DD];        // 8 KB
    __shared__ float enc_s[4][DD];    // 32 KB
    int tid = threadIdx.x;
    int l0 = blockIdx.x * 4;          // 129 chunks cover 513 rows
    int t0 = blockIdx.y * 33;         // y=0: t 0..32, y=1: t 33..64
    int nt = blockIdx.y ? 32 : 33;

    ((float4*)vw_s)[tid] = ((const float4*)vw)[tid];
    ((float4*)vw_s)[tid + 256] = ((const float4*)vw)[tid + 256];
    #pragma unroll
    for (int r = 0; r < 4; r++) {
        int l = l0 + r;
        if (l < LP1) {
            const float4* ep = (const float4*)(enc_proj + (size_t)l * DD);
            ((float4*)enc_s[r])[tid] = ep[tid];
            ((float4*)enc_s[r])[tid + 256] = ep[tid + 256];
        }
    }
    int wave = tid >> 6, lane = tid & 63;
    float vbf = vb[0];

    for (int tt = 0; tt < nt; tt++) {
        int t = t0 + tt;
        __syncthreads();              // previous iteration's Dm_s reads done
        const float4* dp = (const float4*)(Dm + (size_t)t * DD);
        ((float4*)Dm_s)[tid] = dp[tid];
        ((float4*)Dm_s)[tid + 256] = dp[tid + 256];
        __syncthreads();

        int l = l0 + wave;            // one row per wave
        if (l < LP1) {
            const float* er = enc_s[wave];
            float acc = 0.f;
            #pragma unroll 8
            for (int i2 = 0; i2 < 32; i2++) {
                int v = lane + (i2 << 6);
                acc = fmaf(vw_s[v], tanh_fast(er[v] + Dm_s[v]), acc);
            }
            #pragma unroll
            for (int off = 1; off < 64; off <<= 1)
                acc += __shfl_xor(acc, off);
            if (lane == 0)
                outL[(size_t)t * LP1 + l] = acc + vbf;
        }
    }
}

// ---------- K5: losses[t] = logsumexp(logits[t]) - logits[t][tgt] ----------
__global__ __launch_bounds__(256) void loss_kernel(
    const float* __restrict__ LG, const int* __restrict__ pos,
    float* __restrict__ outLoss)
{
    int t = blockIdx.x, tid = threadIdx.x;
    __shared__ float red[256];
    const float* row = LG + (size_t)t * LP1;

    float m = -3.4e38f;
    for (int i = tid; i < LP1; i += 256) m = fmaxf(m, row[i]);
    red[tid] = m; __syncthreads();
    for (int s = 128; s > 0; s >>= 1) {
        if (tid < s) red[tid] = fmaxf(red[tid], red[tid + s]);
        __syncthreads();
    }
    float mx = red[0]; __syncthreads();

    float sum = 0.f;
    for (int i = tid; i < LP1; i += 256)
        sum += exp2f((row[i] - mx) * 1.4426950408889634f);
    red[tid] = sum; __syncthreads();
    for (int s = 128; s > 0; s >>= 1) {
        if (tid < s) red[tid] += red[tid + s];
        __syncthreads();
    }
    if (tid == 0) {
        int tgt = (t < TT - 1) ? pos[t] : (LP1 - 1);
        float lse = mx + 0.6931471805599453f * log2f(red[0]);
        outLoss[t] = lse - row[tgt];
    }
}

// ---------- host ----------
extern "C" void kernel_launch(void* const* d_in, const int* in_sizes, int n_in,
                              void* d_out, int out_size, void* d_ws, size_t ws_size,
                              hipStream_t stream) {
    const float* init_h = (const float*)d_in[0];
    const float* enc    = (const float*)d_in[1];
    const float* seq    = (const float*)d_in[2];
    const int*   pos    = (const int*)d_in[3];
    const float* W_ih   = (const float*)d_in[4];
    const float* W_hh   = (const float*)d_in[5];
    const float* b_ih   = (const float*)d_in[6];
    const float* b_hh   = (const float*)d_in[7];
    const float* We_w   = (const float*)d_in[8];
    const float* We_b   = (const float*)d_in[9];
    const float* Wd_w   = (const float*)d_in[10];
    const float* Wd_b   = (const float*)d_in[11];
    const float* v_w    = (const float*)d_in[12];
    const float* v_b    = (const float*)d_in[13];
    float* out = (float*)d_out;

    // out layout: logits[65*513] | hidden[65*2048] | losses[65]  (fp32)
    float* outL    = out;
    float* outH    = out + (size_t)TT * LP1;
    float* outLoss = outH + (size_t)TT * DD;

    // ws layout: enc_proj | xg | Dm | hX (u32 flag-in-data, 64 KB)
    float* ws = (float*)d_ws;
    float* enc_proj = ws;                               // 513*2048
    float* xg       = enc_proj + (size_t)LP1 * DD;      // 65*8192
    float* Dm       = xg + (size_t)TT * FOURD;          // 65*2048
    uint32* hX      = (uint32*)(Dm + (size_t)TT * DD);  // 2*256*32 u32

    // K0: teacher-forced input-gate biases (also zeroes hX tags)
    xg_kernel<<<dim3(32, TT), 256, 0, stream>>>(W_ih, b_ih, b_hh, seq, pos, xg,
                                                hX);

    // K1: enc_proj = enc @ We^T + We_b   [513 x 2048]  (fp32 in, bf16 MFMA)
    gemm_bf16_kernel<<<dim3(32, 9), 256, 0, stream>>>(enc, We_w, We_b, enc_proj,
                                                      LP1, DD, DD);

    // K2: fused persistent LSTM (cooperative; plain-launch fallback)
    {
        const float* whh = W_hh; const float* ih = init_h; const float* xgp = xg;
        uint32* hx = hX; float* oh = outH;
        void* kargs[] = { (void*)&whh, (void*)&ih, (void*)&xgp, (void*)&hx,
                          (void*)&oh };
        hipError_t e = hipLaunchCooperativeKernel(
            (const void*)lstm_fused_kernel, dim3(NWG), dim3(256),
            kargs, 0, stream);
        if (e != hipSuccess) {
            (void)hipGetLastError();
            lstm_fused_kernel<<<dim3(NWG), dim3(256), 0, stream>>>(
                W_hh, init_h, xg, hX, outH);
        }
    }

    // K3: Dm = H @ Wd^T + Wd_b   [65 x 2048]  (A = outH fp32)
    gemm_bf16_kernel<<<dim3(32, 2), 256, 0, stream>>>(outH, Wd_w, Wd_b, Dm,
                                                      TT, DD, DD);

    // K4: pointer logits (129 l-chunks x 2 t-halves = 258 blocks)
    ptr_kernel<<<dim3(129, 2), 256, 0, stream>>>(enc_proj, Dm, v_w, v_b, outL);

    // K5: losses
    loss_kernel<<<TT, 256, 0, stream>>>(outL, pos, outLoss);
}

// Round 8
// 632.989 us; speedup vs baseline: 1.4258x; 1.4258x over previous
//
#include <hip/hip_runtime.h>

typedef unsigned int uint32;
typedef unsigned short u16;

// Problem constants
#define DD    2048
#define LP1   513
#define TT    65
#define FOURD 8192
#define NWG   256
#define SLOTW 32      // u32 per global slot (8 used, padded to 128 B)
#define PSTR  5       // LDS pair-relay stride per slot (u32; gcd(5,32)=1)

typedef __attribute__((ext_vector_type(8))) short short8;   // 8 bf16 (4 VGPRs)
typedef __attribute__((ext_vector_type(4))) float f32x4;

// ---------- helpers ----------
__device__ __forceinline__ float frcp(float x) { return __builtin_amdgcn_rcpf(x); }
__device__ __forceinline__ float sigm(float x) {
    return frcp(1.f + exp2f(-1.4426950408889634f * x));
}
__device__ __forceinline__ float tanh_fast(float x) {
    float e = exp2f(2.8853900817779268f * x);    // e^(2x)
    return fmaf(-2.f, frcp(1.f + e), 1.f);       // 1 - 2/(1+e^(2x))
}
__device__ __forceinline__ float bflo(uint32 w) {
    union { uint32 i; float f; } c; c.i = w << 16; return c.f;
}
__device__ __forceinline__ float bfhi(uint32 w) {
    union { uint32 i; float f; } c; c.i = w & 0xffff0000u; return c.f;
}
__device__ __forceinline__ uint32 f2bf(float f) {   // RNE, returns low 16
    union { float f; uint32 i; } c; c.f = f;
    return (c.i + 0x7fffu + ((c.i >> 16) & 1u)) >> 16;
}
__device__ __forceinline__ uint32 pack2(float a, float b) {
    return f2bf(a) | (f2bf(b) << 16);
}

#if __has_builtin(__builtin_amdgcn_fdot2_f32_bf16)
#define HAVE_DOT2 1
typedef __attribute__((ext_vector_type(2))) __bf16 bf16x2;
__device__ __forceinline__ float dot2bf(uint32 a, uint32 b, float c) {
    union { uint32 u; bf16x2 v; } x, y; x.u = a; y.u = b;
    return __builtin_amdgcn_fdot2_f32_bf16(x.v, y.v, c, false);
}
#endif

// ---------- K-1: generic fp32 -> bf16 convert (grid*256*8 elems) ----------
__global__ __launch_bounds__(256) void conv_bf16_kernel(
    const float* __restrict__ src, u16* __restrict__ dst)
{
    size_t i = ((size_t)blockIdx.x * 256 + threadIdx.x) * 8;
    float4 a = *(const float4*)(src + i);
    float4 b = *(const float4*)(src + i + 4);
    uint4 o;
    o.x = pack2(a.x, a.y); o.y = pack2(a.z, a.w);
    o.z = pack2(b.x, b.y); o.w = pack2(b.z, b.w);
    *(uint4*)(dst + i) = o;
}

// ---------- K0: xg[t][r] = b_ih[r]+b_hh[r]+W_ih[r,:]@x_t ; zero hX tags ------
__global__ __launch_bounds__(256) void xg_kernel(
    const float* __restrict__ W_ih, const float* __restrict__ b_ih,
    const float* __restrict__ b_hh, const float* __restrict__ seq,
    const int* __restrict__ pos, float* __restrict__ xg,
    uint32* __restrict__ hX)
{
    if (blockIdx.y < 2)   // 2*32 blocks x 256 thr = 16384 = 2*NWG*SLOTW words
        hX[blockIdx.y * 8192 + blockIdx.x * 256 + threadIdx.x] = 0u;
    int t = blockIdx.y;
    int r = blockIdx.x * 256 + threadIdx.x;   // [0, 8192)
    float x0, x1, x2;
    if (t == 0) { x0 = 0.f; x1 = 0.f; x2 = 1.f; }   // special symbol
    else {
        int p = pos[t - 1];
        x0 = seq[p * 3 + 0]; x1 = seq[p * 3 + 1]; x2 = seq[p * 3 + 2];
    }
    float acc = b_ih[r] + b_hh[r];
    acc = fmaf(W_ih[r * 3 + 0], x0, acc);
    acc = fmaf(W_ih[r * 3 + 1], x1, acc);
    acc = fmaf(W_ih[r * 3 + 2], x2, acc);
    xg[(size_t)t * FOURD + r] = acc;
}

// ---------- K1/K3: MFMA GEMM  C[M,N] = A[M,K]@B[N,K]^T + bias, bf16 inputs ----
// 64x64 tile, BK=64, 2-phase prefetch (R5/R6-verified).
#define GLSTR 72
__global__ __launch_bounds__(256) void gemm_bf16_kernel(
    const u16* __restrict__ A, const u16* __restrict__ B,
    const float* __restrict__ bias, float* __restrict__ C,
    int M, int N, int K)
{
    __shared__ u16 As[64 * GLSTR];
    __shared__ u16 Bs[64 * GLSTR];
    int tid = threadIdx.x;
    int wave = tid >> 6, lane = tid & 63;
    int m0 = blockIdx.y * 64, n0 = blockIdx.x * 64;
    int wm = (wave >> 1) * 32, wn = (wave & 1) * 32;
    int srow = tid >> 2, scol = (tid & 3) * 16;

    f32x4 acc[2][2] = {};
    int fr = lane & 15, fq = (lane >> 4) * 8;
    int am = m0 + srow;
    const uint4* ap = (const uint4*)(A + (size_t)am * K + scol);
    const uint4* bp = (const uint4*)(B + (size_t)(n0 + srow) * K + scol);

    // prologue: load tile 0 (two CONSECUTIVE uint4 per thread)
    uint4 a0 = {0,0,0,0}, a1 = a0, b0, b1;
    if (am < M) { a0 = ap[0]; a1 = ap[1]; }
    b0 = bp[0]; b1 = bp[1];

    for (int k0 = 0; k0 < K; k0 += 64) {
        __syncthreads();   // previous tile's fragment reads done
        {
            uint4* ad = (uint4*)(As + srow * GLSTR + scol);
            ad[0] = a0; ad[1] = a1;
            uint4* bd = (uint4*)(Bs + srow * GLSTR + scol);
            bd[0] = b0; bd[1] = b1;
        }
        __syncthreads();

        // issue next tile's loads (overlap with MFMA below)
        if (k0 + 64 < K) {
            int off = (k0 + 64) >> 3;       // uint4 index of element k0+64
            if (am < M) { a0 = ap[off]; a1 = ap[off + 1]; }
            b0 = bp[off]; b1 = bp[off + 1];
        }

        #pragma unroll
        for (int kk = 0; kk < 64; kk += 32) {
            short8 af0 = *(const short8*)(As + (wm + fr) * GLSTR + kk + fq);
            short8 af1 = *(const short8*)(As + (wm + 16 + fr) * GLSTR + kk + fq);
            short8 bf0 = *(const short8*)(Bs + (wn + fr) * GLSTR + kk + fq);
            short8 bf1 = *(const short8*)(Bs + (wn + 16 + fr) * GLSTR + kk + fq);
            acc[0][0] = __builtin_amdgcn_mfma_f32_16x16x32_bf16(af0, bf0, acc[0][0], 0, 0, 0);
            acc[0][1] = __builtin_amdgcn_mfma_f32_16x16x32_bf16(af0, bf1, acc[0][1], 0, 0, 0);
            acc[1][0] = __builtin_amdgcn_mfma_f32_16x16x32_bf16(af1, bf0, acc[1][0], 0, 0, 0);
            acc[1][1] = __builtin_amdgcn_mfma_f32_16x16x32_bf16(af1, bf1, acc[1][1], 0, 0, 0);
        }
    }

    int cn = lane & 15, cr = (lane >> 4) * 4;
    #pragma unroll
    for (int i = 0; i < 2; i++) {
        #pragma unroll
        for (int r = 0; r < 4; r++) {
            int m = m0 + wm + i * 16 + cr + r;
            if (m < M) {
                #pragma unroll
                for (int j = 0; j < 2; j++) {
                    int n = n0 + wn + j * 16 + cn;
                    C[(size_t)m * N + n] = acc[i][j][r] + bias[n];
                }
            }
        }
    }
}

// ---------- K2: fused persistent LSTM -----------------------------------------
// R6 skeleton (W in LDS, flag-in-data global exchange, 2 barriers/step) with:
//  - u32 (tag16|bf16) exchange words (half of R6's poll bytes)
//  - conflict-free LDS pair relay: slot stride 5 u32 (gcd(5,32)=1)
//  - dot2 bf16 MACs when available
#define SMEM_FUSED (32 * 2048 * 2 + TT * 32 * 4 + TT * 8 * 4 + NWG * PSTR * 4)
// = 131072 + 8320 + 2080 + 5120 = 146592 B

__global__ __launch_bounds__(256, 1) void lstm_fused_kernel(
    const float* __restrict__ Whh, const float* __restrict__ init_h,
    const float* __restrict__ xg, uint32* __restrict__ hX,
    float* __restrict__ outH, u16* __restrict__ Hb)
{
    extern __shared__ char smem[];
    u16*    Ws   = (u16*)smem;                       // [32][2048] bf16
    float*  xg_s = (float*)(smem + 32 * 2048 * 2);   // [65][32]
    float*  ho_s = xg_s + TT * 32;                   // [65][8] deferred h out
    uint32* hp_s = (uint32*)(ho_s + TT * 8);         // [256][5] bf16-pair relay

    int tid = threadIdx.x;
    int b = blockIdx.x;                  // owns dims 8b..8b+7
    int wave = tid >> 6, lane = tid & 63;
    int jj = lane & 1;
    int dl = 2 * wave + jj;              // local dim 0..7

    // ---- stage weights: local row r = g*8+j  <->  global row g*2048 + 8b + j
    #pragma unroll 4
    for (int r = 0; r < 32; r++) {
        int g = r >> 3, j = r & 7;
        const float4* s4 =
            (const float4*)(Whh + ((size_t)(g * DD + 8 * b + j)) * DD) + tid * 2;
        float4 x = s4[0], y = s4[1];
        uint4 o;
        o.x = pack2(x.x, x.y); o.y = pack2(x.z, x.w);
        o.z = pack2(y.x, y.y); o.w = pack2(y.z, y.w);
        *(uint4*)(Ws + r * DD + tid * 8) = o;
    }
    // ---- stage this WG's xg slice for all 65 steps
    for (int idx = tid; idx < TT * 32; idx += 256) {
        int t = idx >> 5, rr = idx & 31, g = rr >> 3, j = rr & 7;
        xg_s[idx] = xg[(size_t)t * FOURD + g * DD + 8 * b + j];
    }
    __syncthreads();

    const uint4* Wq = (const uint4*)Ws;   // row r: 256 uint4 (2048 bf16)
    float cst = 0.f;

    for (int t = 0; t < TT; t++) {
        // hp[i][p] = packed bf16 pair for k = i*512 + lane*8 + {2p, 2p+1}
        uint32 hp[4][4];
        if (t == 0) {
            #pragma unroll
            for (int i = 0; i < 4; i++) {
                const float4* p = (const float4*)(init_h + i * 512 + lane * 8);
                float4 x = p[0], y = p[1];
                hp[i][0] = pack2(x.x, x.y); hp[i][1] = pack2(x.z, x.w);
                hp[i][2] = pack2(y.x, y.y); hp[i][3] = pack2(y.z, y.w);
            }
        } else {
            // ---- phase 1: thread tid polls GLOBAL slot tid, packs pairs,
            //      writes 4 u32 to the LDS relay at stride 5 (conflict-free)
            const uint32* gs =
                hX + ((size_t)(((t - 1) & 1) * NWG + tid)) * SLOTW;
            uint32 gv[8];
            #pragma unroll
            for (int j = 0; j < 8; j++)
                gv[j] = __hip_atomic_load(gs + j, __ATOMIC_RELAXED,
                                          __HIP_MEMORY_SCOPE_AGENT);
            for (;;) {
                bool ok = true;
                #pragma unroll
                for (int j = 0; j < 8; j++) ok &= ((gv[j] >> 16) >= (uint32)t);
                if (ok) break;
                __builtin_amdgcn_s_sleep(1);
                #pragma unroll
                for (int j = 0; j < 8; j++)
                    if ((gv[j] >> 16) < (uint32)t)
                        gv[j] = __hip_atomic_load(gs + j, __ATOMIC_RELAXED,
                                                  __HIP_MEMORY_SCOPE_AGENT);
            }
            hp_s[tid * PSTR + 0] = (gv[0] & 0xffffu) | (gv[1] << 16);
            hp_s[tid * PSTR + 1] = (gv[2] & 0xffffu) | (gv[3] << 16);
            hp_s[tid * PSTR + 2] = (gv[4] & 0xffffu) | (gv[5] << 16);
            hp_s[tid * PSTR + 3] = (gv[6] & 0xffffu) | (gv[7] << 16);
            __syncthreads();   // all relay writes visible

            // ---- phase 2: gather my 4 slots (stride-5 -> even bank spread)
            #pragma unroll
            for (int i = 0; i < 4; i++) {
                const uint32* sl = hp_s + (i * 64 + lane) * PSTR;
                hp[i][0] = sl[0]; hp[i][1] = sl[1];
                hp[i][2] = sl[2]; hp[i][3] = sl[3];
            }
        }

        // ---- 8 partial dot products (W from LDS, h pairs in registers)
        float a[4][2];
        #pragma unroll
        for (int g = 0; g < 4; g++)
            #pragma unroll
            for (int q = 0; q < 2; q++) {
                int r = g * 8 + 2 * wave + q;
                float s = 0.f;
                #pragma unroll
                for (int i = 0; i < 4; i++) {
                    uint4 ww = Wq[r * 256 + i * 64 + lane];
#ifdef HAVE_DOT2
                    s = dot2bf(ww.x, hp[i][0], s);
                    s = dot2bf(ww.y, hp[i][1], s);
                    s = dot2bf(ww.z, hp[i][2], s);
                    s = dot2bf(ww.w, hp[i][3], s);
#else
                    s = fmaf(bflo(ww.x), bflo(hp[i][0]), s);
                    s = fmaf(bfhi(ww.x), bfhi(hp[i][0]), s);
                    s = fmaf(bflo(ww.y), bflo(hp[i][1]), s);
                    s = fmaf(bfhi(ww.y), bfhi(hp[i][1]), s);
                    s = fmaf(bflo(ww.z), bflo(hp[i][2]), s);
                    s = fmaf(bfhi(ww.z), bfhi(hp[i][2]), s);
                    s = fmaf(bflo(ww.w), bflo(hp[i][3]), s);
                    s = fmaf(bfhi(ww.w), bfhi(hp[i][3]), s);
#endif
                }
                a[g][q] = s;
            }

        // butterfly reduce over 64 lanes
        #pragma unroll
        for (int off = 1; off < 64; off <<= 1) {
            #pragma unroll
            for (int g = 0; g < 4; g++) {
                a[g][0] += __shfl_xor(a[g][0], off);
                a[g][1] += __shfl_xor(a[g][1], off);
            }
        }
        float si = jj ? a[0][1] : a[0][0];
        float sf = jj ? a[1][1] : a[1][0];
        float sg = jj ? a[2][1] : a[2][0];
        float so = jj ? a[3][1] : a[3][0];
        int xb = t * 32;
        si += xg_s[xb + dl];      sf += xg_s[xb + 8 + dl];
        sg += xg_s[xb + 16 + dl]; so += xg_s[xb + 24 + dl];
        float ig = sigm(si), fg = sigm(sf), gg = tanh_fast(sg), og = sigm(so);
        cst = fmaf(fg, cst, ig * gg);
        float hh = og * tanh_fast(cst);
        if (lane < 2) {
            uint32 wrd = ((uint32)(t + 1) << 16) | f2bf(hh);
            __hip_atomic_store(
                &hX[((size_t)((t & 1) * NWG + b)) * SLOTW + dl], wrd,
                __ATOMIC_RELAXED, __HIP_MEMORY_SCOPE_AGENT);
            ho_s[t * 8 + dl] = hh;            // deferred fp32 h (LDS)
        }
        if (t > 0) __syncthreads();   // hp_s fully consumed before next relay
    }

    // ---- deferred outH / Hb writeback
    __syncthreads();
    for (int idx = tid; idx < TT * 8; idx += 256) {
        int t = idx >> 3, j = idx & 7;
        float hv_ = ho_s[idx];
        outH[(size_t)t * DD + 8 * b + j] = hv_;
        Hb[(size_t)t * DD + 8 * b + j] = (u16)f2bf(hv_);
    }
}

// ---------- K4: logits[t][l] = v_b + sum_v vw[v]*tanh(enc_proj[l][v]+Dm[t][v])
__global__ __launch_bounds__(256) void ptr_kernel(
    const float* __restrict__ enc_proj, const float* __restrict__ Dm,
    const float* __restrict__ vw, const float* __restrict__ vb,
    float* __restrict__ outL)
{
    __shared__ float vw_s[DD];        // 8 KB
    __shared__ float Dm_s[DD];        // 8 KB
    __shared__ float enc_s[4][DD];    // 32 KB
    int tid = threadIdx.x;
    int l0 = blockIdx.x * 4;          // 129 chunks cover 513 rows
    int t0 = blockIdx.y * 33;         // y=0: t 0..32, y=1: t 33..64
    int nt = blockIdx.y ? 32 : 33;

    ((float4*)vw_s)[tid] = ((const float4*)vw)[tid];
    ((float4*)vw_s)[tid + 256] = ((const float4*)vw)[tid + 256];
    #pragma unroll
    for (int r = 0; r < 4; r++) {
        int l = l0 + r;
        if (l < LP1) {
            const float4* ep = (const float4*)(enc_proj + (size_t)l * DD);
            ((float4*)enc_s[r])[tid] = ep[tid];
            ((float4*)enc_s[r])[tid + 256] = ep[tid + 256];
        }
    }
    int wave = tid >> 6, lane = tid & 63;
    float vbf = vb[0];

    for (int tt = 0; tt < nt; tt++) {
        int t = t0 + tt;
        __syncthreads();              // previous iteration's Dm_s reads done
        const float4* dp = (const float4*)(Dm + (size_t)t * DD);
        ((float4*)Dm_s)[tid] = dp[tid];
        ((float4*)Dm_s)[tid + 256] = dp[tid + 256];
        __syncthreads();

        int l = l0 + wave;            // one row per wave
        if (l < LP1) {
            const float* er = enc_s[wave];
            float acc = 0.f;
            #pragma unroll 8
            for (int i2 = 0; i2 < 32; i2++) {
                int v = lane + (i2 << 6);
                acc = fmaf(vw_s[v], tanh_fast(er[v] + Dm_s[v]), acc);
            }
            #pragma unroll
            for (int off = 1; off < 64; off <<= 1)
                acc += __shfl_xor(acc, off);
            if (lane == 0)
                outL[(size_t)t * LP1 + l] = acc + vbf;
        }
    }
}

// ---------- K5: losses[t] = logsumexp(logits[t]) - logits[t][tgt] ----------
__global__ __launch_bounds__(256) void loss_kernel(
    const float* __restrict__ LG, const int* __restrict__ pos,
    float* __restrict__ outLoss)
{
    int t = blockIdx.x, tid = threadIdx.x;
    __shared__ float red[256];
    const float* row = LG + (size_t)t * LP1;

    float m = -3.4e38f;
    for (int i = tid; i < LP1; i += 256) m = fmaxf(m, row[i]);
    red[tid] = m; __syncthreads();
    for (int s = 128; s > 0; s >>= 1) {
        if (tid < s) red[tid] = fmaxf(red[tid], red[tid + s]);
        __syncthreads();
    }
    float mx = red[0]; __syncthreads();

    float sum = 0.f;
    for (int i = tid; i < LP1; i += 256)
        sum += exp2f((row[i] - mx) * 1.4426950408889634f);
    red[tid] = sum; __syncthreads();
    for (int s = 128; s > 0; s >>= 1) {
        if (tid < s) red[tid] += red[tid + s];
        __syncthreads();
    }
    if (tid == 0) {
        int tgt = (t < TT - 1) ? pos[t] : (LP1 - 1);
        float lse = mx + 0.6931471805599453f * log2f(red[0]);
        outLoss[t] = lse - row[tgt];
    }
}

// ---------- host ----------
extern "C" void kernel_launch(void* const* d_in, const int* in_sizes, int n_in,
                              void* d_out, int out_size, void* d_ws, size_t ws_size,
                              hipStream_t stream) {
    const float* init_h = (const float*)d_in[0];
    const float* enc    = (const float*)d_in[1];
    const float* seq    = (const float*)d_in[2];
    const int*   pos    = (const int*)d_in[3];
    const float* W_ih   = (const float*)d_in[4];
    const float* W_hh   = (const float*)d_in[5];
    const float* b_ih   = (const float*)d_in[6];
    const float* b_hh   = (const float*)d_in[7];
    const float* We_w   = (const float*)d_in[8];
    const float* We_b   = (const float*)d_in[9];
    const float* Wd_w   = (const float*)d_in[10];
    const float* Wd_b   = (const float*)d_in[11];
    const float* v_w    = (const float*)d_in[12];
    const float* v_b    = (const float*)d_in[13];
    float* out = (float*)d_out;

    // out layout: logits[65*513] | hidden[65*2048] | losses[65]  (fp32)
    float* outL    = out;
    float* outH    = out + (size_t)TT * LP1;
    float* outLoss = outH + (size_t)TT * DD;

    // ws layout: fp32 region | hX (u32 flag-in-data) | bf16 region
    float* ws = (float*)d_ws;
    float* enc_proj = ws;                               // 513*2048
    float* xg       = enc_proj + (size_t)LP1 * DD;      // 65*8192
    float* Dm       = xg + (size_t)TT * FOURD;          // 65*2048
    uint32* hX      = (uint32*)(Dm + (size_t)TT * DD);  // 2*256*32 u32 = 64 KB
    u16* enc_b = (u16*)(hX + 2 * NWG * SLOTW);          // 513*2048 bf16
    u16* Web   = enc_b + (size_t)LP1 * DD;              // 2048*2048 bf16
    u16* Wdb   = Web + (size_t)DD * DD;                 // 2048*2048 bf16
    u16* Hb    = Wdb + (size_t)DD * DD;                 // 65*2048 bf16

    // opt-in to >64KB dynamic LDS for the fused kernel
    static bool attr_done = false;
    if (!attr_done) {
        (void)hipFuncSetAttribute((const void*)lstm_fused_kernel,
                                  hipFuncAttributeMaxDynamicSharedMemorySize,
                                  SMEM_FUSED);
        attr_done = true;
    }

    // K-1: bf16 copies of enc / We / Wd (GEMM operands)
    conv_bf16_kernel<<<dim3(513), 256, 0, stream>>>(enc, enc_b);
    conv_bf16_kernel<<<dim3(2048), 256, 0, stream>>>(We_w, Web);
    conv_bf16_kernel<<<dim3(2048), 256, 0, stream>>>(Wd_w, Wdb);

    // K0: teacher-forced input-gate biases (also zeroes hX tags)
    xg_kernel<<<dim3(32, TT), 256, 0, stream>>>(W_ih, b_ih, b_hh, seq, pos, xg,
                                                hX);

    // K1: enc_proj = enc @ We^T + We_b   [513 x 2048]
    gemm_bf16_kernel<<<dim3(32, 9), 256, 0, stream>>>(enc_b, Web, We_b, enc_proj,
                                                      LP1, DD, DD);

    // K2: fused persistent LSTM (cooperative; plain-launch fallback)
    {
        const float* whh = W_hh; const float* ih = init_h; const float* xgp = xg;
        uint32* hx = hX; float* oh = outH; u16* hbb = Hb;
        void* kargs[] = { (void*)&whh, (void*)&ih, (void*)&xgp, (void*)&hx,
                          (void*)&oh, (void*)&hbb };
        hipError_t e = hipLaunchCooperativeKernel(
            (const void*)lstm_fused_kernel, dim3(NWG), dim3(256),
            kargs, SMEM_FUSED, stream);
        if (e != hipSuccess) {
            (void)hipGetLastError();
            lstm_fused_kernel<<<dim3(NWG), dim3(256), SMEM_FUSED, stream>>>(
                W_hh, init_h, xg, hX, outH, Hb);
        }
    }

    // K3: Dm = H @ Wd^T + Wd_b   [65 x 2048]
    gemm_bf16_kernel<<<dim3(32, 2), 256, 0, stream>>>(Hb, Wdb, Wd_b, Dm,
                                                      TT, DD, DD);

    // K4: pointer logits (129 l-chunks x 2 t-halves = 258 blocks)
    ptr_kernel<<<dim3(129, 2), 256, 0, stream>>>(enc_proj, Dm, v_w, v_b, outL);

    // K5: losses
    loss_kernel<<<TT, 256, 0, stream>>>(outL, pos, outLoss);
}